// Round 17
// baseline (106.305 us; speedup 1.0000x reference)
//
#include <hip/hip_runtime.h>
#include <math.h>

#define FF 512
#define EE 32
#define RS 40     // LDS row stride in bf16 elements (80 B: 2-way bank alias = free)
#define FCAP 416  // staged-row cap; cnt = 1+Binom(511,0.5), max over fixed inputs ~300
#define NTCAP 26  // FCAP/16

typedef __attribute__((ext_vector_type(8))) short bf16x8;
typedef __attribute__((ext_vector_type(4))) float f32x4;

// sqrt(1/sqrt(32) * log2(e)) — folded into staged FX so MFMA output is the exp2 arg
#define SFOLD 0.5050092f

__device__ __forceinline__ unsigned short f2bf(float x) {
    unsigned int u = __float_as_uint(x);
    return (unsigned short)((u + 0x7fffu + ((u >> 16) & 1u)) >> 16);
}

// accumulate Z (sum of e) and h (sum of e*g) from one C/D tile fragment
__device__ __forceinline__ void zh4(f32x4 d, float4 g, float& z, float& h) {
    float e0 = __builtin_amdgcn_exp2f(d[0]);
    float e1 = __builtin_amdgcn_exp2f(d[1]);
    float e2 = __builtin_amdgcn_exp2f(d[2]);
    float e3 = __builtin_amdgcn_exp2f(d[3]);
    z += (e0 + e1) + (e2 + e3);
    h = fmaf(e0, g.x, fmaf(e1, g.y, fmaf(e2, g.z, fmaf(e3, g.w, h))));
}

// ---- fused pass over NC (<=2) contiguous q-column blocks owned by this wave
// (exact R12 structure — best measured; R13/R15/R16 reschedules all neutral) ----
template <int NC>
__device__ __forceinline__ void fused_cols(const unsigned short* __restrict__ myrow,
                                           const float* __restrict__ gs,
                                           float* __restrict__ a_sh,
                                           int c0, int nt, int cnt, float pad,
                                           int lane, int grp) {
    bf16x8 bf[NC];
#pragma unroll
    for (int c = 0; c < NC; ++c)
        bf[c] = *(const bf16x8*)(myrow + (size_t)(c0 + c) * 16 * RS);
    float zA[NC], zB[NC], hA[NC], hB[NC];
#pragma unroll
    for (int c = 0; c < NC; ++c) { zA[c] = 0.f; zB[c] = 0.f; hA[c] = 0.f; hB[c] = 0.f; }
    const unsigned short* ap = myrow;
    const float* gp = gs + grp * 4;
    int i = 0;
    for (; i + 2 <= nt; i += 2) {
        bf16x8 a0 = *(const bf16x8*)(ap);
        bf16x8 a1 = *(const bf16x8*)(ap + 16 * RS);
        ap += 32 * RS;
        float4 g0 = *(const float4*)(gp);
        float4 g1 = *(const float4*)(gp + 16);
        gp += 32;
#pragma unroll
        for (int c = 0; c < NC; ++c) {
            f32x4 d0 = {0.f, 0.f, 0.f, 0.f};
            f32x4 d1 = {0.f, 0.f, 0.f, 0.f};
            d0 = __builtin_amdgcn_mfma_f32_16x16x32_bf16(a0, bf[c], d0, 0, 0, 0);
            d1 = __builtin_amdgcn_mfma_f32_16x16x32_bf16(a1, bf[c], d1, 0, 0, 0);
            zh4(d0, g0, zA[c], hA[c]);
            zh4(d1, g1, zB[c], hB[c]);
        }
    }
    if (i < nt) {
        bf16x8 a0 = *(const bf16x8*)(ap);
        float4 g0 = *(const float4*)(gp);
#pragma unroll
        for (int c = 0; c < NC; ++c) {
            f32x4 d0 = {0.f, 0.f, 0.f, 0.f};
            d0 = __builtin_amdgcn_mfma_f32_16x16x32_bf16(a0, bf[c], d0, 0, 0, 0);
            zh4(d0, g0, zA[c], hA[c]);
        }
    }
#pragma unroll
    for (int c = 0; c < NC; ++c) {
        float z = zA[c] + zB[c];
        float h = hA[c] + hB[c];
        z += __shfl_xor(z, 16); z += __shfl_xor(z, 32);
        h += __shfl_xor(h, 16); h += __shfl_xor(h, 32);
        int q = (c0 + c) * 16 + lane;
        float val = (lane < 16 && q < cnt) ? h / fmaxf(z - pad, 1e-9f) : 0.f;
        val += __shfl_xor(val, 1);
        val += __shfl_xor(val, 2);
        val += __shfl_xor(val, 4);
        val += __shfl_xor(val, 8);
        if (lane == 0) atomicAdd(a_sh, val);
    }
}

// block=512 (8 waves); LDS ~35 KB -> 4 blocks/CU = 32 waves/CU (wave cap); VGPR cap 64
extern "C" __global__ void __launch_bounds__(512, 8)
model_kernel(const float* __restrict__ X, const float* __restrict__ Xi,
             const float* __restrict__ I, const float* __restrict__ S,
             const float* __restrict__ xi_w, const float* __restrict__ xi_b,
             const float* __restrict__ xs_w, const float* __restrict__ xs_b,
             float* __restrict__ out) {
    const int n = blockIdx.x;
    const int tid = threadIdx.x;
    const int lane = tid & 63;
    const int wv = tid >> 6;          // 8 waves per block
    const int l15 = lane & 15;
    const int grp = lane >> 4;

    __shared__ __align__(16) unsigned short fxb[FCAP * RS];  // 33280 B bf16 (scaled FX)
    __shared__ __align__(16) float gs[FCAP];                 // 1664 B: g_k = SFOLD*FX_k.Iw
    __shared__ float a_sh;
    __shared__ int sh_idx;
    __shared__ int wbase[8];

    const float* Srow = S + (size_t)n * FF;
    const float* Irow = I + (size_t)n * FF;

    // ---- phase 0 (pre-barrier): owner-row staging. Thread tid owns feature
    // row f=tid; xs_w/xs_b loads + r = X*w+b FMAs depend only on tid, so they
    // issue here, overlapped with the one-hot scan and the compaction ballot. ----
    if (Irow[tid] > 0.5f) sh_idx = tid;
    if (tid == 0) a_sh = 0.f;
    bool act = Srow[tid] > 0.f;
    float xv = X[(size_t)n * FF + tid];
    float4 rr[8];
    if (act) {
        const float* wp = xs_w + (size_t)tid * EE;
        const float* bp = xs_b + (size_t)tid * EE;
#pragma unroll
        for (int m = 0; m < 8; ++m) {
            float4 w4 = *(const float4*)(wp + m * 4);
            float4 b4 = *(const float4*)(bp + m * 4);
            rr[m].x = fmaf(xv, w4.x, b4.x);
            rr[m].y = fmaf(xv, w4.y, b4.y);
            rr[m].z = fmaf(xv, w4.z, b4.z);
            rr[m].w = fmaf(xv, w4.w, b4.w);
        }
    }
    unsigned long long mb = __ballot(act);
    int nb = __popcll(mb & ((1ull << lane) - 1ull));
    if (lane == 0) wbase[wv] = __popcll(mb);
    __syncthreads();

    int off = 0;
    for (int i = 0; i < wv; ++i) off += wbase[i];
    int cntr = 0;
#pragma unroll
    for (int i = 0; i < 8; ++i) cntr += wbase[i];
    const int cnt = (cntr < FCAP) ? cntr : FCAP;     // defensive cap (never triggers)
    int nt0 = (cnt + 15) >> 4;
    const int nt = (nt0 < NTCAP) ? nt0 : NTCAP;      // 16x16 tiles per side
    const int ntp16 = nt * 16;
    const int jend = ((nt + 1) >> 1) * 32;           // staged rows padded to pair boundary
    const int idx = sh_idx;

    // ---- phase 1: add broadcast idxb row, scale, pack bf16, write own LDS row;
    // g_k computed as an in-thread dot with broadcast-loaded Iw (no shuffles). ----
    if (act) {
        int pos = off + nb;                          // compacted row index
        if (pos < FCAP) {
            const float* ib  = xs_b + (size_t)idx * EE;   // broadcast (same addr all lanes)
            const float* iwp = xi_w + (size_t)idx * EE;
            float g = 0.f;
#pragma unroll
            for (int m = 0; m < 4; ++m) {
                float4 iA = *(const float4*)(ib + m * 8);
                float4 iB = *(const float4*)(ib + m * 8 + 4);
                float4 wA = *(const float4*)(iwp + m * 8);
                float4 wB = *(const float4*)(iwp + m * 8 + 4);
                float r0 = SFOLD * (rr[2 * m].x + iA.x);
                float r1 = SFOLD * (rr[2 * m].y + iA.y);
                float r2 = SFOLD * (rr[2 * m].z + iA.z);
                float r3 = SFOLD * (rr[2 * m].w + iA.w);
                float r4 = SFOLD * (rr[2 * m + 1].x + iB.x);
                float r5 = SFOLD * (rr[2 * m + 1].y + iB.y);
                float r6 = SFOLD * (rr[2 * m + 1].z + iB.z);
                float r7 = SFOLD * (rr[2 * m + 1].w + iB.w);
                g = fmaf(r0, wA.x, fmaf(r1, wA.y, fmaf(r2, wA.z, fmaf(r3, wA.w, g))));
                g = fmaf(r4, wB.x, fmaf(r5, wB.y, fmaf(r6, wB.z, fmaf(r7, wB.w, g))));
                bf16x8 pk;
                pk[0] = (short)f2bf(r0); pk[1] = (short)f2bf(r1);
                pk[2] = (short)f2bf(r2); pk[3] = (short)f2bf(r3);
                pk[4] = (short)f2bf(r4); pk[5] = (short)f2bf(r5);
                pk[6] = (short)f2bf(r6); pk[7] = (short)f2bf(r7);
                *(bf16x8*)(fxb + (size_t)pos * RS + m * 8) = pk;  // 16B, 16B-aligned
            }
            gs[pos] = g;
        }
    }
    // zero-pad rows [cnt, jend): e contribution exp2(0)=1 (pad-corrected), g=0
    for (int j = cnt + tid; j < jend; j += 512) {
        bf16x8 zk = {0, 0, 0, 0, 0, 0, 0, 0};
#pragma unroll
        for (int m = 0; m < 4; ++m)
            *(bf16x8*)(fxb + (size_t)j * RS + m * 8) = zk;
        gs[j] = 0.f;
    }
    __syncthreads();

    const unsigned short* myrow = fxb + (size_t)l15 * RS + grp * 8;
    const float pad = (float)(ntp16 - cnt);   // zero rows add exp2(0)=1 to each Z

    // uneven contiguous column ownership (R9 scheme; TLP hides imbalance)
    const int cbase = nt >> 3, crem = nt & 7;
    const int ncols = cbase + (wv < crem ? 1 : 0);
    const int c0 = wv * cbase + (wv < crem ? wv : crem);

    // ---- single fused pass: Z_q and h_q together, one exp per pair; NC<=2 only
    // (NC>=3 under the 64-VGPR cap spills — measured R10/R14) ----
    switch (ncols) {
        case 1: fused_cols<1>(myrow, gs, &a_sh, c0, nt, cnt, pad, lane, grp); break;
        case 2: fused_cols<2>(myrow, gs, &a_sh, c0, nt, cnt, pad, lane, grp); break;
        case 3: fused_cols<2>(myrow, gs, &a_sh, c0, nt, cnt, pad, lane, grp);
                fused_cols<1>(myrow, gs, &a_sh, c0 + 2, nt, cnt, pad, lane, grp); break;
        case 4: fused_cols<2>(myrow, gs, &a_sh, c0, nt, cnt, pad, lane, grp);
                fused_cols<2>(myrow, gs, &a_sh, c0 + 2, nt, cnt, pad, lane, grp); break;
        default: break;  // ncols == 0 (tiny cnt only)
    }
    __syncthreads();

    // ---- epilogue: a = (sum_q h_q/Z_q) / (cnt * SFOLD); out = Xi*a - softplus(a)
    if (tid == 0) {
        float a = a_sh / ((float)cnt * SFOLD);
        float xiv = Xi[n];
        float mm = fmaxf(a, 0.f);
        float sp = mm + logf(__expf(a - mm) + __expf(-mm));
        out[n] = xiv * a - sp;  // b-terms cancel
    }
}

extern "C" void kernel_launch(void* const* d_in, const int* in_sizes, int n_in,
                              void* d_out, int out_size, void* d_ws, size_t ws_size,
                              hipStream_t stream) {
    const float* X    = (const float*)d_in[0];
    const float* Xi   = (const float*)d_in[1];
    const float* I    = (const float*)d_in[2];
    const float* S    = (const float*)d_in[3];
    const float* xi_w = (const float*)d_in[4];
    const float* xi_b = (const float*)d_in[5];
    const float* xs_w = (const float*)d_in[6];
    const float* xs_b = (const float*)d_in[7];
    float* out = (float*)d_out;
    const int N = in_sizes[1];  // Xi is [N]
    hipLaunchKernelGGL(model_kernel, dim3(N), dim3(512), 0, stream,
                       X, Xi, I, S, xi_w, xi_b, xs_w, xs_b, out);
}